// Round 2
// baseline (165.783 us; speedup 1.0000x reference)
//
#include <hip/hip_runtime.h>
#include <hip/hip_bf16.h>

typedef __bf16 bf16_t;
typedef __bf16 bf16x4 __attribute__((ext_vector_type(4)));
typedef __bf16 bf16x8 __attribute__((ext_vector_type(8)));
typedef float floatx4 __attribute__((ext_vector_type(4)));

#define N_NODES 4096
#define F_IN 128
#define NUM_HEADS 4
#define D_HID 64
#define F_OUT 256  // NUM_HEADS * D_HID
#define NEG_SLOPE 0.2f
#define LOG2E 1.4426950408889634f

// ---------------------------------------------------------------------------
// Kernel 1: projections (f32 in; GB bf16 fragment-linear + el/er f32 out).
//   GB[h][j>>5][f>>4][lane=(f&15)+16*((j>>3)&3)][j&7]  (1 KB per B-fragment)
//   el/er are PRE-SCALED by log2(e) so attn can use v_exp_f32 (2^x) directly.
// 1024 blocks x 384 threads; block handles 4 nodes.
// ---------------------------------------------------------------------------
__global__ __launch_bounds__(384) void proj_kernel(
    const float* __restrict__ hmat, const float* __restrict__ Wp,
    const float* __restrict__ Wa, const float* __restrict__ wattn,
    bf16_t* __restrict__ GB, float* __restrict__ el, float* __restrict__ er)
{
    const int t = threadIdx.x;
    const int j0 = blockIdx.x * 4;

    float acc[4] = {0.f, 0.f, 0.f, 0.f};

    const float* wptr;
    int stride;
    if (t < 256) { wptr = Wp + t;         stride = 256; }
    else         { wptr = Wa + (t - 256); stride = 128; }

    const float* hbase = hmat + (size_t)j0 * F_IN;

    for (int m = 0; m < F_IN; m += 4) {
        const float w0 = wptr[(size_t)(m + 0) * stride];
        const float w1 = wptr[(size_t)(m + 1) * stride];
        const float w2 = wptr[(size_t)(m + 2) * stride];
        const float w3 = wptr[(size_t)(m + 3) * stride];
#pragma unroll
        for (int jl = 0; jl < 4; ++jl) {
            const float4 hv = *reinterpret_cast<const float4*>(&hbase[jl * F_IN + m]);
            acc[jl] = fmaf(hv.w, w3, fmaf(hv.z, w2, fmaf(hv.y, w1, fmaf(hv.x, w0, acc[jl]))));
        }
    }

    if (t < 256) {
        const int h = t >> 6, f = t & 63;
        bf16x4 o;
#pragma unroll
        for (int q = 0; q < 4; ++q) o[q] = (bf16_t)acc[q];
        const size_t base = ((((size_t)h * 128 + (j0 >> 5)) * 4 + (f >> 4)) * 64
                             + (f & 15) + 16 * ((j0 >> 3) & 3)) * 8 + (j0 & 7);
        *reinterpret_cast<bf16x4*>(&GB[base]) = o;
    } else {
        const int ta = t - 256;          // waves 4,5; 32-lane group per head
        const int ha = ta >> 5, k = ta & 31;
        const float wl = wattn[k] * LOG2E, wr = wattn[32 + k] * LOG2E;
#pragma unroll
        for (int jl = 0; jl < 4; ++jl) {
            float vl = acc[jl] * wl;
            float vr = acc[jl] * wr;
#pragma unroll
            for (int s = 16; s >= 1; s >>= 1) {
                vl += __shfl_xor(vl, s, 64);
                vr += __shfl_xor(vr, s, 64);
            }
            if (k == 0) {
                el[ha * N_NODES + j0 + jl] = vl;
                er[ha * N_NODES + j0 + jl] = vr;
            }
        }
    }
}

// ---------------------------------------------------------------------------
// Kernel 2: barrier-free fused attention. NO LDS.
// Grid (128 i-tiles of 32 rows, njc) x 256 threads (4 waves = 4 heads).
// Each wave owns (head hh, rows i0..i0+31, j-chunk jc): it computes its MFMA
// A-fragments (P values) directly in registers -- lane m+16*quad holds
// P[row m][j = kt*32 + quad*8 + q], built from el[hh][i0+m] (+16 for hi half),
// er[hh][j] and adj[i0+m][j].  B-fragments are read straight from L2-resident
// GB (coalesced 16 B/lane).  Denominator via ones-B MFMA as before.
// Zero __syncthreads, zero LDS: waves are fully independent.
// ---------------------------------------------------------------------------
__global__ __launch_bounds__(256, 4) void attn_kernel(
    const float* __restrict__ adj, const bf16_t* __restrict__ GB,
    const float* __restrict__ el, const float* __restrict__ er,
    float* __restrict__ numout, float* __restrict__ den_g,
    int njc, int ntiles)
{
    const int tid  = threadIdx.x;
    const int i0   = blockIdx.x * 32;
    const int jc   = blockIdx.y;
    const int jT0  = jc * ntiles * 64;
    const int hh   = tid >> 6;            // head = wave
    const int lane = tid & 63;
    const int m    = lane & 15;
    const int quad = lane >> 4;

    // per-lane scalars (log2e-prescaled at proj time)
    const float el_lo = el[hh * N_NODES + i0 + m];
    const float el_hi = el[hh * N_NODES + i0 + 16 + m];
    const float* adj_lo = adj + (size_t)(i0 + m) * N_NODES;
    const float* adj_hi = adj_lo + (size_t)16 * N_NODES;
    const float* erp    = er + hh * N_NODES;
    const bf16_t* gb_h  = GB + (size_t)hh * (128 * 4 * 512) + lane * 8;

    floatx4 accL0 = {0.f, 0.f, 0.f, 0.f};
    floatx4 accL1 = accL0, accL2 = accL0, accL3 = accL0, accdL = accL0;
    floatx4 accH0 = accL0, accH1 = accL0, accH2 = accL0, accH3 = accL0, accdH = accL0;
    bf16x8 ones;
#pragma unroll
    for (int q = 0; q < 8; ++q) ones[q] = (bf16_t)1.0f;

    for (int k = 0; k < ntiles; ++k) {
        const int jT = jT0 + k * 64;
#pragma unroll
        for (int kt = 0; kt < 2; ++kt) {
            const int jb = jT + kt * 32 + quad * 8;
            // loads first: adj (2 rows x 8), er (8), GB B-frags (4 x 16B)
            const float4 aL0 = *reinterpret_cast<const float4*>(adj_lo + jb);
            const float4 aL1 = *reinterpret_cast<const float4*>(adj_lo + jb + 4);
            const float4 aH0 = *reinterpret_cast<const float4*>(adj_hi + jb);
            const float4 aH1 = *reinterpret_cast<const float4*>(adj_hi + jb + 4);
            const float4 e0  = *reinterpret_cast<const float4*>(erp + jb);
            const float4 e1  = *reinterpret_cast<const float4*>(erp + jb + 4);
            const bf16_t* gp = gb_h + (size_t)((jT >> 5) + kt) * (4 * 512);
            const bf16x8 b0 = *reinterpret_cast<const bf16x8*>(gp);
            const bf16x8 b1 = *reinterpret_cast<const bf16x8*>(gp + 512);
            const bf16x8 b2 = *reinterpret_cast<const bf16x8*>(gp + 1024);
            const bf16x8 b3 = *reinterpret_cast<const bf16x8*>(gp + 1536);

            const float ev[8]  = {e0.x, e0.y, e0.z, e0.w, e1.x, e1.y, e1.z, e1.w};
            const float avL[8] = {aL0.x, aL0.y, aL0.z, aL0.w, aL1.x, aL1.y, aL1.z, aL1.w};
            const float avH[8] = {aH0.x, aH0.y, aH0.z, aH0.w, aH1.x, aH1.y, aH1.z, aH1.w};

            bf16x8 afL, afH;
#pragma unroll
            for (int q = 0; q < 8; ++q) {
                const float sL = el_lo + ev[q];
                const float sH = el_hi + ev[q];
                const float pL = __builtin_amdgcn_exp2f(fmaxf(sL, NEG_SLOPE * sL));
                const float pH = __builtin_amdgcn_exp2f(fmaxf(sH, NEG_SLOPE * sH));
                afL[q] = (bf16_t)(avL[q] >= 0.5f ? pL : 0.0f);
                afH[q] = (bf16_t)(avH[q] >= 0.5f ? pH : 0.0f);
            }

            accdL = __builtin_amdgcn_mfma_f32_16x16x32_bf16(afL, ones, accdL, 0, 0, 0);
            accdH = __builtin_amdgcn_mfma_f32_16x16x32_bf16(afH, ones, accdH, 0, 0, 0);
            accL0 = __builtin_amdgcn_mfma_f32_16x16x32_bf16(afL, b0, accL0, 0, 0, 0);
            accH0 = __builtin_amdgcn_mfma_f32_16x16x32_bf16(afH, b0, accH0, 0, 0, 0);
            accL1 = __builtin_amdgcn_mfma_f32_16x16x32_bf16(afL, b1, accL1, 0, 0, 0);
            accH1 = __builtin_amdgcn_mfma_f32_16x16x32_bf16(afH, b1, accH1, 0, 0, 0);
            accL2 = __builtin_amdgcn_mfma_f32_16x16x32_bf16(afL, b2, accL2, 0, 0, 0);
            accH2 = __builtin_amdgcn_mfma_f32_16x16x32_bf16(afH, b2, accH2, 0, 0, 0);
            accL3 = __builtin_amdgcn_mfma_f32_16x16x32_bf16(afL, b3, accL3, 0, 0, 0);
            accH3 = __builtin_amdgcn_mfma_f32_16x16x32_bf16(afH, b3, accH3, 0, 0, 0);
        }
    }

    // epilogue: C/D row = quad*4 + r (+16 for hi), col = m; den in accd[r]
    float* nrow = numout + (size_t)jc * ((size_t)N_NODES * F_OUT);
    const int ibL = i0 + quad * 4;
    const int ibH = ibL + 16;
#pragma unroll
    for (int r = 0; r < 4; ++r) {
        float* dL = nrow + (size_t)(ibL + r) * F_OUT + hh * D_HID + m;
        dL[0]  = accL0[r];
        dL[16] = accL1[r];
        dL[32] = accL2[r];
        dL[48] = accL3[r];
        float* dH = nrow + (size_t)(ibH + r) * F_OUT + hh * D_HID + m;
        dH[0]  = accH0[r];
        dH[16] = accH1[r];
        dH[32] = accH2[r];
        dH[48] = accH3[r];
    }
    if (m == 0) {
#pragma unroll
        for (int r = 0; r < 4; ++r) {
            den_g[((size_t)jc * N_NODES + ibL + r) * NUM_HEADS + hh] = accdL[r];
            den_g[((size_t)jc * N_NODES + ibH + r) * NUM_HEADS + hh] = accdH[r];
        }
    }
}

// ---------------------------------------------------------------------------
// Kernel 3: sum chunk partials, divide, store f32. Templated njc (full unroll).
// ---------------------------------------------------------------------------
template<int NJC>
__global__ __launch_bounds__(256) void reduce_kernel(
    const float* __restrict__ num, const float* __restrict__ den,
    float* __restrict__ out)
{
    const int idx = blockIdx.x * 256 + threadIdx.x;  // 0 .. N*F_OUT-1
    const int i  = idx >> 8;
    const int c  = idx & 255;
    const int hh = c >> 6;
    float n = 0.f, d = 0.f;
#pragma unroll
    for (int jc = 0; jc < NJC; ++jc) {
        n += num[(size_t)jc * ((size_t)N_NODES * F_OUT) + idx];
        d += den[((size_t)jc * N_NODES + i) * NUM_HEADS + hh];
    }
    out[idx] = n / d;
}

// ---------------------------------------------------------------------------
extern "C" void kernel_launch(void* const* d_in, const int* in_sizes, int n_in,
                              void* d_out, int out_size, void* d_ws, size_t ws_size,
                              hipStream_t stream)
{
    const float* hmat = (const float*)d_in[0];   // (4096, 128) f32
    const float* adj  = (const float*)d_in[1];   // (4096, 4096) f32
    const float* Wp   = (const float*)d_in[2];   // (128, 256) f32
    const float* Wa   = (const float*)d_in[3];   // (128, 128) f32
    const float* watt = (const float*)d_in[4];   // (64,) f32
    float* out = (float*)d_out;                  // (4096, 256) f32

    char* ws = (char*)d_ws;
    bf16_t* GB = (bf16_t*)ws;                                  // 2 MiB
    float*  el = (float*)(ws + (2ull << 20));                  // 64 KiB
    float*  er = (float*)(ws + (2ull << 20) + (64ull << 10));  // 64 KiB
    const size_t baseoff = (2ull << 20) + (128ull << 10);

    const size_t num_bytes = (size_t)N_NODES * F_OUT * 4;          // 4 MiB per chunk
    const size_t den_bytes = (size_t)N_NODES * NUM_HEADS * 4;      // 64 KiB per chunk
    const int njc = (ws_size >= baseoff + 8 * (num_bytes + den_bytes)) ? 8
                  : (ws_size >= baseoff + 4 * (num_bytes + den_bytes)) ? 4 : 2;

    float* num = (float*)(ws + baseoff);
    float* den = (float*)(ws + baseoff + (size_t)njc * num_bytes);

    proj_kernel<<<1024, 384, 0, stream>>>(hmat, Wp, Wa, watt, GB, el, er);
    attn_kernel<<<dim3(128, njc), 256, 0, stream>>>(adj, GB, el, er, num, den,
                                                    njc, (N_NODES / njc) / 64);
    if (njc == 8)      reduce_kernel<8><<<(N_NODES * F_OUT) / 256, 256, 0, stream>>>(num, den, out);
    else if (njc == 4) reduce_kernel<4><<<(N_NODES * F_OUT) / 256, 256, 0, stream>>>(num, den, out);
    else               reduce_kernel<2><<<(N_NODES * F_OUT) / 256, 256, 0, stream>>>(num, den, out);
}

// Round 3
// 159.851 us; speedup vs baseline: 1.0371x; 1.0371x over previous
//
#include <hip/hip_runtime.h>
#include <hip/hip_bf16.h>

typedef __bf16 bf16_t;
typedef __bf16 bf16x4 __attribute__((ext_vector_type(4)));
typedef __bf16 bf16x8 __attribute__((ext_vector_type(8)));
typedef float floatx4 __attribute__((ext_vector_type(4)));
typedef unsigned int u32;

#define N_NODES 4096
#define F_IN 128
#define NUM_HEADS 4
#define D_HID 64
#define F_OUT 256  // NUM_HEADS * D_HID
#define NEG_SLOPE 0.2f
#define LOG2E 1.4426950408889634f
#define NWORDS 128  // mask u32 words per adjacency row (4096/32)

// ---------------------------------------------------------------------------
// Kernel 0: adjacency -> packed bitmask (1 bit per edge, >=0.5 threshold).
// Pure streaming: 64 MiB read, 2 MiB write. Removes all HBM-latency loads
// from the attention inner loop (mask is L2-resident everywhere after this).
// word w covers adj[w*32 .. w*32+31]; bit b of word = (adj[w*32+b] >= 0.5).
// ---------------------------------------------------------------------------
__global__ __launch_bounds__(256) void mask_kernel(
    const float* __restrict__ adj, u32* __restrict__ maskw)
{
    const int w = blockIdx.x * 256 + threadIdx.x;   // 0 .. 4096*128-1
    const float* src = adj + (size_t)w * 32;
    u32 bits = 0;
#pragma unroll
    for (int c = 0; c < 8; ++c) {
        const float4 v = *reinterpret_cast<const float4*>(src + c * 4);
        bits |= (u32)(v.x >= 0.5f) << (4 * c + 0);
        bits |= (u32)(v.y >= 0.5f) << (4 * c + 1);
        bits |= (u32)(v.z >= 0.5f) << (4 * c + 2);
        bits |= (u32)(v.w >= 0.5f) << (4 * c + 3);
    }
    maskw[w] = bits;
}

// ---------------------------------------------------------------------------
// Kernel 1: projections (f32 in; GB bf16 fragment-linear + el/er f32 out).
//   GB[h][j>>5][f>>4][lane=(f&15)+16*((j>>3)&3)][j&7]  (1 KB per B-fragment)
//   el/er PRE-SCALED by log2(e) so attn uses v_exp_f32 (2^x) directly.
// 1024 blocks x 384 threads; block handles 4 nodes.
// ---------------------------------------------------------------------------
__global__ __launch_bounds__(384) void proj_kernel(
    const float* __restrict__ hmat, const float* __restrict__ Wp,
    const float* __restrict__ Wa, const float* __restrict__ wattn,
    bf16_t* __restrict__ GB, float* __restrict__ el, float* __restrict__ er)
{
    const int t = threadIdx.x;
    const int j0 = blockIdx.x * 4;

    float acc[4] = {0.f, 0.f, 0.f, 0.f};

    const float* wptr;
    int stride;
    if (t < 256) { wptr = Wp + t;         stride = 256; }
    else         { wptr = Wa + (t - 256); stride = 128; }

    const float* hbase = hmat + (size_t)j0 * F_IN;

    for (int m = 0; m < F_IN; m += 4) {
        const float w0 = wptr[(size_t)(m + 0) * stride];
        const float w1 = wptr[(size_t)(m + 1) * stride];
        const float w2 = wptr[(size_t)(m + 2) * stride];
        const float w3 = wptr[(size_t)(m + 3) * stride];
#pragma unroll
        for (int jl = 0; jl < 4; ++jl) {
            const float4 hv = *reinterpret_cast<const float4*>(&hbase[jl * F_IN + m]);
            acc[jl] = fmaf(hv.w, w3, fmaf(hv.z, w2, fmaf(hv.y, w1, fmaf(hv.x, w0, acc[jl]))));
        }
    }

    if (t < 256) {
        const int h = t >> 6, f = t & 63;
        bf16x4 o;
#pragma unroll
        for (int q = 0; q < 4; ++q) o[q] = (bf16_t)acc[q];
        const size_t base = ((((size_t)h * 128 + (j0 >> 5)) * 4 + (f >> 4)) * 64
                             + (f & 15) + 16 * ((j0 >> 3) & 3)) * 8 + (j0 & 7);
        *reinterpret_cast<bf16x4*>(&GB[base]) = o;
    } else {
        const int ta = t - 256;          // waves 4,5; 32-lane group per head
        const int ha = ta >> 5, k = ta & 31;
        const float wl = wattn[k] * LOG2E, wr = wattn[32 + k] * LOG2E;
#pragma unroll
        for (int jl = 0; jl < 4; ++jl) {
            float vl = acc[jl] * wl;
            float vr = acc[jl] * wr;
#pragma unroll
            for (int s = 16; s >= 1; s >>= 1) {
                vl += __shfl_xor(vl, s, 64);
                vr += __shfl_xor(vr, s, 64);
            }
            if (k == 0) {
                el[ha * N_NODES + j0 + jl] = vl;
                er[ha * N_NODES + j0 + jl] = vr;
            }
        }
    }
}

// ---------------------------------------------------------------------------
// Kernel 2: barrier-free fused attention, no LDS, no HBM-latency loads.
// Grid (128 i-tiles of 32 rows, njc) x 256 threads (4 waves = 4 heads).
// Wave (head hh) builds its MFMA A-fragments (P values) in registers from
// el (per-lane scalar), er (L2 broadcast) and the packed adjacency bitmask
// (L2-resident 2 MiB). B-fragments read from L2-resident GB. All next-step
// inputs are register-prefetched (depth 1) so per-wave stall ~0.
// One step s = one 32-column block (j32): 10 MFMAs, ~300 VALU cycles.
// ---------------------------------------------------------------------------
__global__ __launch_bounds__(256, 4) void attn_kernel(
    const u32* __restrict__ maskw, const bf16_t* __restrict__ GB,
    const float* __restrict__ el, const float* __restrict__ er,
    float* __restrict__ numout, float* __restrict__ den_g,
    int ntiles)
{
    const int tid  = threadIdx.x;
    const int i0   = blockIdx.x * 32;
    const int jc   = blockIdx.y;
    const int hh   = tid >> 6;            // head = wave
    const int lane = tid & 63;
    const int m    = lane & 15;
    const int quad = lane >> 4;
    const int NS   = ntiles * 2;          // steps of 32 columns
    const int j32_0 = (jc * ntiles * 64) >> 5;

    const float el_lo = el[hh * N_NODES + i0 + m];
    const float el_hi = el[hh * N_NODES + i0 + 16 + m];
    const u32* mrowL = maskw + (size_t)(i0 + m) * NWORDS;
    const u32* mrowH = mrowL + (size_t)16 * NWORDS;
    const float* erp = er + hh * N_NODES + quad * 8;
    const bf16_t* gb = GB + (size_t)hh * (128 * 4 * 512) + lane * 8;

    floatx4 accL0 = {0.f, 0.f, 0.f, 0.f};
    floatx4 accL1 = accL0, accL2 = accL0, accL3 = accL0, accdL = accL0;
    floatx4 accH0 = accL0, accH1 = accL0, accH2 = accL0, accH3 = accL0, accdH = accL0;
    bf16x8 ones;
#pragma unroll
    for (int q = 0; q < 8; ++q) ones[q] = (bf16_t)1.0f;

    // prologue: load step-0 set
    u32 mLc = mrowL[j32_0], mHc = mrowH[j32_0];
    float4 e0c = *reinterpret_cast<const float4*>(erp + j32_0 * 32);
    float4 e1c = *reinterpret_cast<const float4*>(erp + j32_0 * 32 + 4);
    const bf16_t* gp0 = gb + (size_t)j32_0 * 2048;
    bf16x8 b0c = *reinterpret_cast<const bf16x8*>(gp0);
    bf16x8 b1c = *reinterpret_cast<const bf16x8*>(gp0 + 512);
    bf16x8 b2c = *reinterpret_cast<const bf16x8*>(gp0 + 1024);
    bf16x8 b3c = *reinterpret_cast<const bf16x8*>(gp0 + 1536);

    for (int s = 0; s < NS; ++s) {
        // ---- prefetch step s+1 (covers L2 latency under this step's VALU) ----
        u32 mLn = 0, mHn = 0;
        float4 e0n = {0.f, 0.f, 0.f, 0.f}, e1n = e0n;
        bf16x8 b0n = {}, b1n = {}, b2n = {}, b3n = {};
        if (s + 1 < NS) {
            const int jn = j32_0 + s + 1;
            mLn = mrowL[jn];
            mHn = mrowH[jn];
            e0n = *reinterpret_cast<const float4*>(erp + jn * 32);
            e1n = *reinterpret_cast<const float4*>(erp + jn * 32 + 4);
            const bf16_t* gp = gb + (size_t)jn * 2048;
            b0n = *reinterpret_cast<const bf16x8*>(gp);
            b1n = *reinterpret_cast<const bf16x8*>(gp + 512);
            b2n = *reinterpret_cast<const bf16x8*>(gp + 1024);
            b3n = *reinterpret_cast<const bf16x8*>(gp + 1536);
        }
        // ---- compute P fragments for this step ----
        const u32 byL = (mLc >> (quad * 8)) & 0xff;
        const u32 byH = (mHc >> (quad * 8)) & 0xff;
        const float ev[8] = {e0c.x, e0c.y, e0c.z, e0c.w, e1c.x, e1c.y, e1c.z, e1c.w};
        bf16x8 afL, afH;
#pragma unroll
        for (int q = 0; q < 8; ++q) {
            const float sL = el_lo + ev[q];
            const float sH = el_hi + ev[q];
            const float pL = __builtin_amdgcn_exp2f(fmaxf(sL, NEG_SLOPE * sL));
            const float pH = __builtin_amdgcn_exp2f(fmaxf(sH, NEG_SLOPE * sH));
            afL[q] = (bf16_t)(((byL >> q) & 1u) ? pL : 0.0f);
            afH[q] = (bf16_t)(((byH >> q) & 1u) ? pH : 0.0f);
        }
        // ---- MFMAs ----
        accdL = __builtin_amdgcn_mfma_f32_16x16x32_bf16(afL, ones, accdL, 0, 0, 0);
        accdH = __builtin_amdgcn_mfma_f32_16x16x32_bf16(afH, ones, accdH, 0, 0, 0);
        accL0 = __builtin_amdgcn_mfma_f32_16x16x32_bf16(afL, b0c, accL0, 0, 0, 0);
        accH0 = __builtin_amdgcn_mfma_f32_16x16x32_bf16(afH, b0c, accH0, 0, 0, 0);
        accL1 = __builtin_amdgcn_mfma_f32_16x16x32_bf16(afL, b1c, accL1, 0, 0, 0);
        accH1 = __builtin_amdgcn_mfma_f32_16x16x32_bf16(afH, b1c, accH1, 0, 0, 0);
        accL2 = __builtin_amdgcn_mfma_f32_16x16x32_bf16(afL, b2c, accL2, 0, 0, 0);
        accH2 = __builtin_amdgcn_mfma_f32_16x16x32_bf16(afH, b2c, accH2, 0, 0, 0);
        accL3 = __builtin_amdgcn_mfma_f32_16x16x32_bf16(afL, b3c, accL3, 0, 0, 0);
        accH3 = __builtin_amdgcn_mfma_f32_16x16x32_bf16(afH, b3c, accH3, 0, 0, 0);
        // ---- rotate prefetched set in ----
        mLc = mLn; mHc = mHn; e0c = e0n; e1c = e1n;
        b0c = b0n; b1c = b1n; b2c = b2n; b3c = b3n;
    }

    // epilogue: C/D row = quad*4 + r (+16 for hi), col = m; den in accd[r]
    float* nrow = numout + (size_t)jc * ((size_t)N_NODES * F_OUT);
    const int ibL = i0 + quad * 4;
    const int ibH = ibL + 16;
#pragma unroll
    for (int r = 0; r < 4; ++r) {
        float* dL = nrow + (size_t)(ibL + r) * F_OUT + hh * D_HID + m;
        dL[0]  = accL0[r];
        dL[16] = accL1[r];
        dL[32] = accL2[r];
        dL[48] = accL3[r];
        float* dH = nrow + (size_t)(ibH + r) * F_OUT + hh * D_HID + m;
        dH[0]  = accH0[r];
        dH[16] = accH1[r];
        dH[32] = accH2[r];
        dH[48] = accH3[r];
    }
    if (m == 0) {
#pragma unroll
        for (int r = 0; r < 4; ++r) {
            den_g[((size_t)jc * N_NODES + ibL + r) * NUM_HEADS + hh] = accdL[r];
            den_g[((size_t)jc * N_NODES + ibH + r) * NUM_HEADS + hh] = accdH[r];
        }
    }
}

// ---------------------------------------------------------------------------
// Kernel 3: sum chunk partials, divide, store f32 (float4-vectorized).
// ---------------------------------------------------------------------------
template<int NJC>
__global__ __launch_bounds__(256) void reduce_kernel(
    const float* __restrict__ num, const float* __restrict__ den,
    float* __restrict__ out)
{
    const int t4   = blockIdx.x * 256 + threadIdx.x;  // 0 .. N*F_OUT/4-1
    const int base = t4 * 4;
    const int i  = base >> 8;
    const int hh = (base & 255) >> 6;                 // same head for all 4 ch
    float4 n = {0.f, 0.f, 0.f, 0.f};
    float d = 0.f;
#pragma unroll
    for (int jc = 0; jc < NJC; ++jc) {
        const float4 v = *reinterpret_cast<const float4*>(
            num + (size_t)jc * ((size_t)N_NODES * F_OUT) + base);
        n.x += v.x; n.y += v.y; n.z += v.z; n.w += v.w;
        d += den[((size_t)jc * N_NODES + i) * NUM_HEADS + hh];
    }
    const float rd = 1.0f / d;
    float4 o = {n.x * rd, n.y * rd, n.z * rd, n.w * rd};
    *reinterpret_cast<float4*>(out + base) = o;
}

// ---------------------------------------------------------------------------
extern "C" void kernel_launch(void* const* d_in, const int* in_sizes, int n_in,
                              void* d_out, int out_size, void* d_ws, size_t ws_size,
                              hipStream_t stream)
{
    const float* hmat = (const float*)d_in[0];   // (4096, 128) f32
    const float* adj  = (const float*)d_in[1];   // (4096, 4096) f32
    const float* Wp   = (const float*)d_in[2];   // (128, 256) f32
    const float* Wa   = (const float*)d_in[3];   // (128, 128) f32
    const float* watt = (const float*)d_in[4];   // (64,) f32
    float* out = (float*)d_out;                  // (4096, 256) f32

    char* ws = (char*)d_ws;
    bf16_t* GB   = (bf16_t*)ws;                                  // 2 MiB
    float*  el   = (float*)(ws + (2ull << 20));                  // 64 KiB
    float*  er   = (float*)(ws + (2ull << 20) + (64ull << 10));  // 64 KiB
    u32*    mskw = (u32*)(ws + (2ull << 20) + (128ull << 10));   // 2 MiB
    const size_t baseoff = (4ull << 20) + (128ull << 10);

    const size_t num_bytes = (size_t)N_NODES * F_OUT * 4;          // 4 MiB per chunk
    const size_t den_bytes = (size_t)N_NODES * NUM_HEADS * 4;      // 64 KiB per chunk
    // ws >= ~34.6 MB proven (njc=8 ran with old layout). New baseoff is 2 MiB
    // larger; prefer 8 if it still fits, else 4 (always fits), else 2.
    const int njc = (ws_size >= baseoff + 8 * (num_bytes + den_bytes)) ? 8
                  : (ws_size >= baseoff + 4 * (num_bytes + den_bytes)) ? 4 : 2;

    float* num = (float*)(ws + baseoff);
    float* den = (float*)(ws + baseoff + (size_t)njc * num_bytes);

    proj_kernel<<<1024, 384, 0, stream>>>(hmat, Wp, Wa, watt, GB, el, er);
    mask_kernel<<<(N_NODES * NWORDS) / 256, 256, 0, stream>>>(adj, mskw);
    attn_kernel<<<dim3(128, njc), 256, 0, stream>>>(mskw, GB, el, er, num, den,
                                                    (N_NODES / njc) / 64);
    if (njc == 8)      reduce_kernel<8><<<(N_NODES * F_OUT) / 1024, 256, 0, stream>>>(num, den, out);
    else if (njc == 4) reduce_kernel<4><<<(N_NODES * F_OUT) / 1024, 256, 0, stream>>>(num, den, out);
    else               reduce_kernel<2><<<(N_NODES * F_OUT) / 1024, 256, 0, stream>>>(num, den, out);
}